// Round 6
// baseline (1000.549 us; speedup 1.0000x reference)
//
#include <hip/hip_runtime.h>

// Depthwise 7x7 VALID conv, fp32, NCHW.
// x: (16,256,128,128), w: (256,7,7), out: (16,256,122,122)
// No LDS. Each thread: 4x4 output micro-tile; 10 rows x (2 float4 + 1 float2)
// loads, compiler-chosen hoisting within a 5-waves/EU register budget.
// Weights forced to SGPRs via readfirstlane. Edge tiles overlap with
// identical values; single store mask on the last column group.

#define BATCH 16
#define CHAN  256
#define H_IN  128
#define W_IN  128
#define KS    7
#define H_OUT 122
#define W_OUT 122

#define RB 4           // output rows per thread
#define CB 4           // output cols per thread

typedef float v2f __attribute__((ext_vector_type(2)));

__device__ __forceinline__ float sgpr_bcast(float v) {
    return __int_as_float(__builtin_amdgcn_readfirstlane(__float_as_int(v)));
}

__global__ __launch_bounds__(256, 5)
void dwconv7x7_kernel(const float* __restrict__ x,
                      const float* __restrict__ w,
                      float* __restrict__ out) {
    // ---- chunked XCD swizzle: same-image blocks land on one XCD ----
    const int s   = blockIdx.x;                 // 16384 blocks, %8 == 0
    const int wid = (s & 7) * 2048 + (s >> 3);  // bijective
    const int img = wid >> 2;                   // b*CHAN + c
    const int t   = wid & 3;
    const int ch  = img & (CHAN - 1);

    const int x0 = (t & 1) * 60;                // 0 or 60 (keeps ox % 4 == 0)
    const int y0 = (t >> 1) * 58;               // 0 or 58

    const int tx = threadIdx.x & 15;            // 16 col groups x 4 = 64 cols
    const int ty = threadIdx.x >> 4;            // 16 row groups x 4 = 64 rows

    const int ox = x0 + tx * CB;                // <=120, multiple of 4
    const int oy = y0 + ty * RB;                // <=118; input rows <=127

    // ---- weights: block-uniform -> force into SGPRs ----
    const float* __restrict__ wp = w + ch * (KS * KS);
    float wr[KS * KS];
    #pragma unroll
    for (int i = 0; i < KS * KS; ++i) wr[i] = sgpr_bcast(wp[i]);

    // input cols needed: ox..ox+9.  Third load clamps to 126 only when
    // ox==120; its garbage feeds only outputs >= col 122 (masked below).
    const int c2 = (ox + 8 <= W_IN - 2) ? ox + 8 : W_IN - 2;

    const float* __restrict__ xp =
        x + (size_t)img * (H_IN * W_IN) + (size_t)oy * W_IN;

    float acc[RB][CB] = {};

    #pragma unroll
    for (int r = 0; r < RB + KS - 1; ++r) {     // 10 input rows
        const float* row = xp + r * W_IN;
        const float4 a0 = *reinterpret_cast<const float4*>(row + ox);
        const float4 a1 = *reinterpret_cast<const float4*>(row + ox + 4);
        const v2f    a2 = *reinterpret_cast<const v2f*>(row + c2);
        const float win[10] = {a0.x, a0.y, a0.z, a0.w,
                               a1.x, a1.y, a1.z, a1.w,
                               a2.x, a2.y};
        #pragma unroll
        for (int i = 0; i < RB; ++i) {
            const int ky = r - i;
            if (ky >= 0 && ky < KS) {
                #pragma unroll
                for (int kx = 0; kx < KS; ++kx) {
                    const float wv = wr[ky * KS + kx];
                    #pragma unroll
                    for (int cc = 0; cc < CB; ++cc)
                        acc[i][cc] = fmaf(win[kx + cc], wv, acc[i][cc]);
                }
            }
        }
    }

    // ---- stores: float2; only ox==120 needs the second pair masked ----
    float* __restrict__ op =
        out + (size_t)img * (H_OUT * W_OUT) + (size_t)oy * W_OUT + ox;
    const bool hi_ok = (ox + 2 < W_OUT);
    #pragma unroll
    for (int i = 0; i < RB; ++i) {
        float* q = op + i * W_OUT;
        v2f v0; v0.x = acc[i][0]; v0.y = acc[i][1];
        __builtin_nontemporal_store(v0, reinterpret_cast<v2f*>(q));
        if (hi_ok) {
            v2f v1; v1.x = acc[i][2]; v1.y = acc[i][3];
            __builtin_nontemporal_store(v1, reinterpret_cast<v2f*>(q) + 1);
        }
    }
}

extern "C" void kernel_launch(void* const* d_in, const int* in_sizes, int n_in,
                              void* d_out, int out_size, void* d_ws, size_t ws_size,
                              hipStream_t stream) {
    const float* x = (const float*)d_in[0];
    const float* w = (const float*)d_in[1];
    float* out = (float*)d_out;

    // 4 blocks per image (2x2 tiles of 64x64), 4096 images
    dim3 grid(4 * BATCH * CHAN, 1, 1);   // 16384 blocks
    dim3 block(256, 1, 1);
    dwconv7x7_kernel<<<grid, block, 0, stream>>>(x, w, out);
}

// Round 7
// 423.150 us; speedup vs baseline: 2.3645x; 2.3645x over previous
//
#include <hip/hip_runtime.h>

// Depthwise 7x7 VALID conv, fp32, NCHW.
// x: (16,256,128,128), w: (256,7,7), out: (16,256,122,122)
// R3 structure (no LDS, straight unrolled row loop, compiler-chosen load
// hoisting, NO launch-bounds min-waves hint) with float4 row loads:
// each thread: 4x8 output micro-tile, 10 rows x 4 float4 (16B-aligned).
// Weights in SGPRs via readfirstlane. tx=15 computes 8 cols, stores 2.

#define BATCH 16
#define CHAN  256
#define H_IN  128
#define W_IN  128
#define KS    7
#define H_OUT 122
#define W_OUT 122

#define RB 4           // output rows per thread
#define CB 8           // output cols per thread

typedef float v2f __attribute__((ext_vector_type(2)));

__device__ __forceinline__ float sgpr_bcast(float v) {
    return __int_as_float(__builtin_amdgcn_readfirstlane(__float_as_int(v)));
}

__global__ __launch_bounds__(256)
void dwconv7x7_kernel(const float* __restrict__ x,
                      const float* __restrict__ w,
                      float* __restrict__ out) {
    const int img = blockIdx.y;                 // b*CHAN + c
    const int ch  = img & (CHAN - 1);

    const int tx = threadIdx.x & 15;            // 16 col groups x 8 = 128 cols
    const int ty = threadIdx.x >> 4;            // 16 row groups x 4 = 64 rows

    const int ox = tx * CB;                     // 0..120, multiple of 8
    const int y0 = (blockIdx.x == 0) ? 0 : (H_OUT - 64);   // 0 or 58
    const int oy = y0 + ty * RB;                // <=118; input rows oy..oy+9 <=127

    // ---- weights: block-uniform -> force into SGPRs ----
    const float* __restrict__ wp = w + ch * (KS * KS);
    float wr[KS * KS];
    #pragma unroll
    for (int i = 0; i < KS * KS; ++i) wr[i] = sgpr_bcast(wp[i]);

    // column chunk bases: multiples of 4, clamped in-bounds (clamped garbage
    // feeds only outputs >= col 122, which are masked at store)
    const int c2 = (ox + 8  <= W_IN - 4) ? ox + 8  : W_IN - 4;   // clamp tx=15
    const int c3 = (ox + 12 <= W_IN - 4) ? ox + 12 : W_IN - 4;   // clamp tx>=14

    const float* __restrict__ xp =
        x + (size_t)img * (H_IN * W_IN) + (size_t)oy * W_IN;

    float acc[RB][CB] = {};

    #pragma unroll
    for (int r = 0; r < RB + KS - 1; ++r) {     // 10 input rows
        const float* row = xp + r * W_IN;
        const float4 a0 = *reinterpret_cast<const float4*>(row + ox);
        const float4 a1 = *reinterpret_cast<const float4*>(row + ox + 4);
        const float4 a2 = *reinterpret_cast<const float4*>(row + c2);
        const float4 a3 = *reinterpret_cast<const float4*>(row + c3);
        const float win[16] = {a0.x, a0.y, a0.z, a0.w,
                               a1.x, a1.y, a1.z, a1.w,
                               a2.x, a2.y, a2.z, a2.w,
                               a3.x, a3.y, a3.z, a3.w};
        #pragma unroll
        for (int i = 0; i < RB; ++i) {
            const int ky = r - i;
            if (ky >= 0 && ky < KS) {
                #pragma unroll
                for (int kx = 0; kx < KS; ++kx) {
                    const float wv = wr[ky * KS + kx];
                    #pragma unroll
                    for (int cc = 0; cc < CB; ++cc)
                        acc[i][cc] = fmaf(win[kx + cc], wv, acc[i][cc]);
                }
            }
        }
    }

    // ---- stores: float2 (8B-aligned); tx=15 stores only cols 120-121 ----
    float* __restrict__ op =
        out + (size_t)img * (H_OUT * W_OUT) + (size_t)oy * W_OUT + ox;
    #pragma unroll
    for (int i = 0; i < RB; ++i) {
        float* q = op + i * W_OUT;
        #pragma unroll
        for (int j = 0; j < CB / 2; ++j) {
            if (ox + 2 * j + 2 <= W_OUT) {
                v2f v;
                v.x = acc[i][2 * j];
                v.y = acc[i][2 * j + 1];
                __builtin_nontemporal_store(v, reinterpret_cast<v2f*>(q) + j);
            }
        }
    }
}

extern "C" void kernel_launch(void* const* d_in, const int* in_sizes, int n_in,
                              void* d_out, int out_size, void* d_ws, size_t ws_size,
                              hipStream_t stream) {
    const float* x = (const float*)d_in[0];
    const float* w = (const float*)d_in[1];
    float* out = (float*)d_out;

    dim3 grid(2, BATCH * CHAN, 1);   // 2 row-tiles x 4096 images
    dim3 block(256, 1, 1);
    dwconv7x7_kernel<<<grid, block, 0, stream>>>(x, w, out);
}